// Round 3
// baseline (293.251 us; speedup 1.0000x reference)
//
#include <hip/hip_runtime.h>

// DayAdapter: out[b,t,e] = softsign( x[b,t,:] @ W[day[b]] + bias[day[b]] )
// Round 3: software-pipelined K-loop. Double-buffered LDS A+B, ONE barrier per
// K-iter; next tile's B (global_load_lds) and A (global->regs) issued right
// after the barrier so they are in flight across the whole MFMA phase -- the
// vmcnt(0) drain at the next barrier finds them complete. 512-thread blocks
// (8 waves, 2x4 wave grid) so 2 blocks/CU still gives 16 waves/CU at 64 KB LDS.

#define DIM 512
#define SEQ 1024
#define NDAYS 24
#define BM 128
#define BN 128
#define BK 64
#define NITER (DIM / BK)   // 8

typedef __bf16 bf16x8 __attribute__((ext_vector_type(8)));
typedef float  f32x4  __attribute__((ext_vector_type(4)));

__device__ __forceinline__ void gll16(const void* g, void* l) {
    __builtin_amdgcn_global_load_lds(
        (const __attribute__((address_space(1))) unsigned int*)g,
        (__attribute__((address_space(3))) unsigned int*)l,
        16, 0, 0);
}

// ---- kernel 1: Wt[d][n][k] = bf16(W[d][k][n]) ----
__global__ __launch_bounds__(256)
void transpose_w_kernel(const float* __restrict__ W, __bf16* __restrict__ Wt) {
    __shared__ __bf16 T[32][33];
    const int d  = blockIdx.z;
    const int k0 = blockIdx.x * 32;
    const int n0 = blockIdx.y * 32;
    const int tx = threadIdx.x & 31;
    const int ty = threadIdx.x >> 5;
    const float* Wd = W + (size_t)d * DIM * DIM;
    #pragma unroll
    for (int i = 0; i < 4; ++i) {
        const int k = ty + i * 8;
        T[tx][k] = (__bf16)Wd[(size_t)(k0 + k) * DIM + n0 + tx];
    }
    __syncthreads();
    __bf16* Wtd = Wt + (size_t)d * DIM * DIM;
    #pragma unroll
    for (int i = 0; i < 4; ++i) {
        const int n = ty + i * 8;
        Wtd[(size_t)(n0 + n) * DIM + k0 + tx] = T[n][tx];
    }
}

// ---- kernel 2: main GEMM + bias + softsign ----
__global__ __launch_bounds__(512, 4)
void day_adapter_kernel(const float* __restrict__ x,
                        const int*   __restrict__ day_ids,
                        const __bf16* __restrict__ Wt,
                        const float* __restrict__ bias,
                        float*       __restrict__ out)
{
    // Both tiles stored as 16B chunks, XOR-swizzled: logical (row, c) lives at
    // physical chunk c ^ (row&7). Row stride 64 bf16 = 128 B = 8 chunks.
    __shared__ __align__(16) __bf16 As[2][BM * BK];   // 2 x 16 KB
    __shared__ __align__(16) __bf16 Bs[2][BN * BK];   // 2 x 16 KB

    // XCD swizzle: the 4 n-tiles of one (m,b) share blockIdx mod 8 -> same XCD.
    const int L  = blockIdx.x;
    const int g  = (L >> 3) & 3;
    const int mb = (L & 7) | ((L >> 5) << 3);
    const int m  = mb & 7;
    const int bb = mb >> 3;

    const int n0  = g * BN;
    const int m0  = m * BM;
    const int tid = threadIdx.x;
    const int day = day_ids[bb];

    const float*  xb  = x   + (size_t)bb  * SEQ * DIM + (size_t)m0 * DIM;
    const __bf16* Wtb = Wt  + (size_t)day * DIM * DIM + (size_t)n0 * DIM;
    float*        ob  = out + (size_t)bb  * SEQ * DIM + (size_t)m0 * DIM + n0;

    const int wave = tid >> 6;
    const int lane = tid & 63;
    const int wm   = (wave & 1) * 64;        // 2 m-waves
    const int wn   = (wave >> 1) * 32;       // 4 n-waves
    const int l15  = lane & 15;
    const int quad = lane >> 4;

    // A staging: thread -> row ar = tid>>2 (0..127), col group acg = tid&3
    // (16 f32 = 4 float4 at cols acg*16 + 4p) -> 2 swizzled 16B LDS chunks.
    const int ar  = tid >> 2;
    const int acg = tid & 3;

    f32x4 acc[4][2];
    const f32x4 zero = {0.f, 0.f, 0.f, 0.f};
    #pragma unroll
    for (int i = 0; i < 4; ++i) { acc[i][0] = zero; acc[i][1] = zero; }

    float4 areg[4];

    // ---- prologue: issue tile-0 loads ----
    #pragma unroll
    for (int p = 0; p < 2; ++p) {
        const int s = p * 512 + tid;
        const int n = s >> 3;
        const int c = (s & 7) ^ (n & 7);
        gll16(Wtb + (size_t)n * DIM + c * 8,
              (char*)Bs[0] + (size_t)(p * 512 + (tid & ~63)) * 16);
    }
    #pragma unroll
    for (int p = 0; p < 4; ++p)
        areg[p] = *(const float4*)(xb + (size_t)ar * DIM + acg * 16 + p * 4);

    for (int it = 0; it < NITER; ++it) {
        const int cur = it & 1;
        const int nxt = cur ^ 1;

        // ---- commit A(it) from regs: cvt f32->bf16, 2 swizzled ds_write_b128 ----
        {
            bf16x8 w0, w1;
            w0[0] = (__bf16)areg[0].x; w0[1] = (__bf16)areg[0].y;
            w0[2] = (__bf16)areg[0].z; w0[3] = (__bf16)areg[0].w;
            w0[4] = (__bf16)areg[1].x; w0[5] = (__bf16)areg[1].y;
            w0[6] = (__bf16)areg[1].z; w0[7] = (__bf16)areg[1].w;
            w1[0] = (__bf16)areg[2].x; w1[1] = (__bf16)areg[2].y;
            w1[2] = (__bf16)areg[2].z; w1[3] = (__bf16)areg[2].w;
            w1[4] = (__bf16)areg[3].x; w1[5] = (__bf16)areg[3].y;
            w1[6] = (__bf16)areg[3].z; w1[7] = (__bf16)areg[3].w;
            const int c0 = (2 * acg)     ^ (ar & 7);
            const int c1 = (2 * acg + 1) ^ (ar & 7);
            *(bf16x8*)&As[cur][ar * BK + c0 * 8] = w0;
            *(bf16x8*)&As[cur][ar * BK + c1 * 8] = w1;
        }

        // ONE barrier per iter: drains B gll(it) [vmcnt] + A writes [lgkm].
        __syncthreads();

        // ---- prefetch tile it+1 (in flight across the MFMA phase) ----
        if (it + 1 < NITER) {
            const int kk = (it + 1) * BK;
            #pragma unroll
            for (int p = 0; p < 2; ++p) {
                const int s = p * 512 + tid;
                const int n = s >> 3;
                const int c = (s & 7) ^ (n & 7);
                gll16(Wtb + (size_t)n * DIM + kk + c * 8,
                      (char*)Bs[nxt] + (size_t)(p * 512 + (tid & ~63)) * 16);
            }
            #pragma unroll
            for (int p = 0; p < 4; ++p)
                areg[p] = *(const float4*)(xb + (size_t)ar * DIM + kk + acg * 16 + p * 4);
        }

        // ---- compute on buffers [cur] ----
        #pragma unroll
        for (int ks = 0; ks < 2; ++ks) {
            bf16x8 af[4], bfr[2];
            #pragma unroll
            for (int i = 0; i < 4; ++i) {
                const int mr = wm + i * 16 + l15;
                const int c  = (ks * 4 + quad) ^ (mr & 7);
                af[i] = *(const bf16x8*)&As[cur][mr * BK + c * 8];
            }
            #pragma unroll
            for (int j = 0; j < 2; ++j) {
                const int nr = wn + j * 16 + l15;
                const int c  = (ks * 4 + quad) ^ (nr & 7);
                bfr[j] = *(const bf16x8*)&Bs[cur][nr * BK + c * 8];
            }
            #pragma unroll
            for (int i = 0; i < 4; ++i)
                #pragma unroll
                for (int j = 0; j < 2; ++j)
                    acc[i][j] = __builtin_amdgcn_mfma_f32_16x16x32_bf16(
                        af[i], bfr[j], acc[i][j], 0, 0, 0);
        }
        // NOTE: no second barrier. Next iter writes buffers [nxt]; buffers [cur]
        // are rewritten two iters later, after the intervening barrier has
        // drained everyone's ds_reads (lgkmcnt(0) at s_barrier).
    }

    // ---- epilogue: bias + softsign ----
    float bv[2];
    #pragma unroll
    for (int j = 0; j < 2; ++j)
        bv[j] = bias[(size_t)day * DIM + n0 + wn + j * 16 + l15];

    #pragma unroll
    for (int i = 0; i < 4; ++i) {
        const int rbase = wm + i * 16 + quad * 4;        // C/D: row = quad*4 + reg
        #pragma unroll
        for (int j = 0; j < 2; ++j) {
            const int col = wn + j * 16 + l15;           // C/D: col = lane&15
            #pragma unroll
            for (int r = 0; r < 4; ++r) {
                const float y = acc[i][j][r] + bv[j];
                ob[(size_t)(rbase + r) * DIM + col] = y / (1.0f + fabsf(y));
            }
        }
    }
}

extern "C" void kernel_launch(void* const* d_in, const int* in_sizes, int n_in,
                              void* d_out, int out_size, void* d_ws, size_t ws_size,
                              hipStream_t stream) {
    const float* x       = (const float*)d_in[0];
    const int*   day_ids = (const int*)  d_in[1];
    const float* W       = (const float*)d_in[2];
    const float* bias    = (const float*)d_in[3];
    float*       out     = (float*)d_out;
    __bf16*      Wt      = (__bf16*)d_ws;   // 24*512*512*2 = 12.58 MB

    dim3 tgrid(DIM / 32, DIM / 32, NDAYS);
    transpose_w_kernel<<<tgrid, 256, 0, stream>>>(W, Wt);

    day_adapter_kernel<<<dim3(2048), 512, 0, stream>>>(x, day_ids, Wt, bias, out);
}